// Round 6
// baseline (772.750 us; speedup 1.0000x reference)
//
#include <hip/hip_runtime.h>
#include <hip/hip_bf16.h>

#define T_DIM 256
#define B_DIM 128
#define C_DIM 1024
#define H_DIM 1024
#define L_DIM 6
#define NC_DIM 1000
#define M_DIM (T_DIM * B_DIM)    // 32768
#define BH_DIM (B_DIM * H_DIM)   // 131072

typedef __attribute__((ext_vector_type(8))) short bf16x8;
typedef __attribute__((ext_vector_type(16))) float f32x16;

__device__ __forceinline__ float bf2f(unsigned short u) {
  union { unsigned int i; float f; } v; v.i = ((unsigned int)u) << 16; return v.f;
}
__device__ __forceinline__ unsigned short f2bf(float f) {
  union { float f; unsigned int i; } v; v.f = f;
  unsigned int r = v.i + 0x7fffu + ((v.i >> 16) & 1u);  // RNE
  return (unsigned short)(r >> 16);
}

__device__ __forceinline__ void gload_lds16(const void* g, void* l) {
  __builtin_amdgcn_global_load_lds(
      (const __attribute__((address_space(1))) unsigned int*)g,
      (__attribute__((address_space(3))) unsigned int*)l, 16, 0, 0);
}

// ---------------- x f32 -> bf16 convert ----------------
__global__ __launch_bounds__(256) void f32_to_bf16_kernel(
    const float* __restrict__ in, unsigned short* __restrict__ out, int n4) {
  int stride = gridDim.x * blockDim.x;
  for (int i = blockIdx.x * blockDim.x + threadIdx.x; i < n4; i += stride) {
    float4 v = ((const float4*)in)[i];
    ushort4 o;
    o.x = f2bf(v.x); o.y = f2bf(v.y); o.z = f2bf(v.z); o.w = f2bf(v.w);
    ((ushort4*)out)[i] = o;
  }
}

// ---------------- W (L,C,H) f32 -> Wt (L,H,C) bf16 ----------------
__global__ __launch_bounds__(256) void wtrans_kernel(
    const float* __restrict__ W, unsigned short* __restrict__ Wt) {
  __shared__ float tile[32][33];
  int l = blockIdx.z;
  const float* Wl = W + (size_t)l * C_DIM * H_DIM;
  unsigned short* Wtl = Wt + (size_t)l * C_DIM * H_DIM;
  int h0 = blockIdx.x * 32, c0 = blockIdx.y * 32;
  int tx = threadIdx.x, ty = threadIdx.y;  // 32 x 8
#pragma unroll
  for (int i = 0; i < 32; i += 8)
    tile[ty + i][tx] = Wl[(size_t)(c0 + ty + i) * H_DIM + h0 + tx];
  __syncthreads();
#pragma unroll
  for (int i = 0; i < 32; i += 8)
    Wtl[(size_t)(h0 + ty + i) * C_DIM + c0 + tx] = f2bf(tile[tx][ty + i]);
}

// ---------------- GEMM 256x256 tile, BK=32, 4-buffer, 32x32x16 MFMA ----------------
// Z(bf16, M x H) = A(bf16, M x K) * Wt(bf16, N x K)^T, fused BN partial stats (f32).
// 8 waves (2M x 4N), per-wave 128x64 output = 4x2 32x32 frags (16 f32 each = 128 acc).
// LDS: 4 buffers x (A 16KB + B 16KB) = 128 KiB; zero-conflict XOR swizzle
//   (16B chunk ^= (row>>1)&3; round-3 verified SQ_LDS_BANK_CONFLICT = 0).
// Cross-tile register double-buffer: batch kk1(t) read at tile top, kk0(t+1)
// mid-tile -> every ds_read batch gets a full MFMA phase of latency cover.
// Counted vmcnt(4) + ONE barrier per K-tile; tile t+3 stays in flight.
#define NT 32  // K / 32

__global__ __launch_bounds__(512, 2) void gemm_kernel(
    const unsigned short* __restrict__ A, const unsigned short* __restrict__ Bt,
    unsigned short* __restrict__ Z, float* __restrict__ psum, float* __restrict__ psqs) {
  extern __shared__ char lds[];
  int bid = blockIdx.x;              // 512 blocks, %8==0 -> bijective XCD swizzle
  int swz = (bid & 7) * 64 + (bid >> 3);
  int tm = swz >> 2, tn = swz & 3;   // 128 x 4 tiles
  int tid = threadIdx.x;
  int wv = tid >> 6, ln = tid & 63;
  int wm = wv >> 2, wn = wv & 3;     // 2 x 4 wave grid
  int lr = ln & 31;

  // ---- staging precompute (pre-swizzled global source, linear LDS dest) ----
  const char* Asrc = (const char*)A + (size_t)tm * 256 * 2048;   // row stride 2048B
  const char* Bsrc = (const char*)Bt + (size_t)tn * 256 * 2048;
  int p0 = wv * 1024 + ln * 16;          // physical byte (load 0, rows 0..127)
  int p1 = 8192 + wv * 1024 + ln * 16;   // physical byte (load 1, rows 128..255)
  int l0 = p0 ^ (((p0 >> 7) & 3) << 4);  // involution: chunk ^= (row>>1)&3
  int l1 = p1 ^ (((p1 >> 7) & 3) << 4);
  int ro0 = (p0 >> 6) * 2048 + (l0 & 63);
  int ro1 = (p1 >> 6) * 2048 + (l1 & 63);
  int dst0 = wv * 1024;                  // wave-uniform LDS bases (+ lane*16 by HW)
  int dst1 = 8192 + wv * 1024;

  // 32x32 fragment read offsets (within a 32-row frag block):
  // row = lr, k-chunk = (ln>>5) + 2*kk, swizzled by ((row>>1)&3)
  int swzk = (lr >> 1) & 3;
  int loff0 = lr * 64 + ((((ln >> 5)) ^ swzk) << 4);
  int loff1 = lr * 64 + ((((ln >> 5) + 2) ^ swzk) << 4);

  f32x16 acc[4][2];
#pragma unroll
  for (int m = 0; m < 4; ++m)
#pragma unroll
    for (int n = 0; n < 2; ++n)
#pragma unroll
      for (int r = 0; r < 16; ++r) acc[m][n][r] = 0.f;

  auto stageA = [&](int t) {
    char* b = lds + ((t & 3) * 32768); int ko = t * 64;
    gload_lds16(Asrc + ro0 + ko, b + dst0);
    gload_lds16(Asrc + ro1 + ko, b + dst1);
  };
  auto stageB = [&](int t) {
    char* b = lds + ((t & 3) * 32768); int ko = t * 64;
    gload_lds16(Bsrc + ro0 + ko, b + 16384 + dst0);
    gload_lds16(Bsrc + ro1 + ko, b + 16384 + dst1);
  };

  bf16x8 a0[4], b0[2], a1[4], b1[2];
  auto readf = [&](int t, int loff, bf16x8* a, bf16x8* b) {
    const char* buf = lds + ((t & 3) * 32768);
    const char* Ab = buf + wm * 8192;          // 128 rows * 64B
    const char* Bb = buf + 16384 + wn * 4096;  // 64 rows * 64B
#pragma unroll
    for (int m = 0; m < 4; ++m) a[m] = *(const bf16x8*)(Ab + m * 2048 + loff);
#pragma unroll
    for (int n = 0; n < 2; ++n) b[n] = *(const bf16x8*)(Bb + n * 2048 + loff);
  };
  auto domfma = [&](bf16x8* a, bf16x8* b) {
    __builtin_amdgcn_s_setprio(1);
#pragma unroll
    for (int m = 0; m < 4; ++m)
#pragma unroll
      for (int n = 0; n < 2; ++n)
        acc[m][n] = __builtin_amdgcn_mfma_f32_32x32x16_bf16(a[m], b[n], acc[m][n], 0, 0, 0);
    __builtin_amdgcn_s_setprio(0);
  };

  // prologue: tiles 0,1,2 in flight (12 loads); wait tiles 0,1 (vmcnt 4 = tile 2)
  stageA(0); stageB(0); stageA(1); stageB(1); stageA(2); stageB(2);
  asm volatile("s_waitcnt vmcnt(4)" ::: "memory");
  __builtin_amdgcn_s_barrier();
  readf(0, loff0, a0, b0);

  for (int t = 0; t < NT; ++t) {
    if (t <= NT - 4) stageA(t + 3);
    readf(t, loff1, a1, b1);        // batch kk1(t): covered by MFMA(kk0)
    domfma(a0, b0);
    if (t <= NT - 4) stageB(t + 3);
    if (t < NT - 1) readf(t + 1, loff0, a0, b0);  // batch kk0(t+1): covered by MFMA(kk1)
    domfma(a1, b1);
    if (t < NT - 1) {
      if (t <= NT - 4) { asm volatile("s_waitcnt vmcnt(4)" ::: "memory"); }
      else             { asm volatile("s_waitcnt vmcnt(0)" ::: "memory"); }
      __builtin_amdgcn_s_barrier();
    }
  }

  // ---- epilogue: fused BN partial stats (exact f32) + bf16 Z write ----
  // 32x32 C/D layout (m74/m101): col = ln&31, row = (reg&3) + 8*(reg>>2) + 4*(ln>>5)
  float s[2], q[2];
#pragma unroll
  for (int n = 0; n < 2; ++n) {
    float sv = 0.f, qv = 0.f;
#pragma unroll
    for (int m = 0; m < 4; ++m)
#pragma unroll
      for (int r = 0; r < 16; ++r) { float v = acc[m][n][r]; sv += v; qv += v * v; }
    s[n] = sv; q[n] = qv;
  }
#pragma unroll
  for (int n = 0; n < 2; ++n) { s[n] += __shfl_xor(s[n], 32); q[n] += __shfl_xor(q[n], 32); }
  float* red = (float*)lds;  // buffer-0 region, dead after tile 28
  if (ln < 32) {
#pragma unroll
    for (int n = 0; n < 2; ++n) {
      red[wm * 256 + wn * 64 + n * 32 + lr] = s[n];
      red[512 + wm * 256 + wn * 64 + n * 32 + lr] = q[n];
    }
  }
  __syncthreads();
  if (tid < 256) {
    psum[(size_t)tm * H_DIM + tn * 256 + tid] = red[tid] + red[256 + tid];
  } else if (tid < 512) {
    int c = tid - 256;
    psqs[(size_t)tm * H_DIM + tn * 256 + c] = red[512 + c] + red[768 + c];
  }
  int colb = tn * 256 + wn * 64 + lr;
  int rowb = tm * 256 + wm * 128 + ((ln >> 5) << 2);
#pragma unroll
  for (int m = 0; m < 4; ++m)
#pragma unroll
    for (int n = 0; n < 2; ++n)
#pragma unroll
      for (int g = 0; g < 4; ++g) {
        unsigned short* zp = Z + (size_t)(rowb + m * 32 + 8 * g) * H_DIM + colb + n * 32;
#pragma unroll
        for (int r = 0; r < 4; ++r) zp[(size_t)r * H_DIM] = f2bf(acc[m][n][4 * g + r]);
      }
}

// ---------------- BN finalize: sum 128 partials per channel ----------------
__global__ __launch_bounds__(256) void bn_finalize_kernel(
    const float* __restrict__ psum, const float* __restrict__ psqs,
    const float* __restrict__ gamma, const float* __restrict__ beta,
    float* __restrict__ ss) {
  int c = blockIdx.x * blockDim.x + threadIdx.x;
  float s = 0.f, q = 0.f;
  for (int i = 0; i < 128; ++i) {
    s += psum[(size_t)i * H_DIM + c];
    q += psqs[(size_t)i * H_DIM + c];
  }
  const float invN = 1.0f / (float)M_DIM;
  float mean = s * invN;
  float var = q * invN - mean * mean;
  float sc = gamma[c] * rsqrtf(var + 1e-5f);
  ss[c] = sc;
  ss[H_DIM + c] = beta[c] - mean * sc;
}

// ---------------- fused BN-apply + IndRNN recurrence (2 ch/thread, bf16 Z) ----------------
// 32-deep static double-buffered prefetch (compile-time indices, rule #20).
__global__ __launch_bounds__(256) void bn_recur_kernel(
    const unsigned short* __restrict__ Z, const float* __restrict__ ss,
    const float* __restrict__ u, unsigned short* __restrict__ Hout) {
  int i2 = blockIdx.x * 256 + threadIdx.x;  // pair index, 0..BH/2-1
  int h0 = (i2 & (H_DIM / 2 - 1)) * 2;
  float sc0 = ss[h0], sc1 = ss[h0 + 1];
  float sh0 = ss[H_DIM + h0], sh1 = ss[H_DIM + h0 + 1];
  float u0 = u[h0], u1 = u[h0 + 1];
  float hv0 = 0.f, hv1 = 0.f;
  const size_t ST = BH_DIM / 2;
  const unsigned int* Zt = (const unsigned int*)Z + i2;
  unsigned int* Ht = (unsigned int*)Hout + i2;

  unsigned int za[32], zb[32];
#pragma unroll
  for (int j = 0; j < 32; ++j) za[j] = Zt[(size_t)j * ST];

#pragma unroll
  for (int blk = 0; blk < 4; ++blk) {
    int tA = blk * 64;
#pragma unroll
    for (int j = 0; j < 32; ++j) zb[j] = Zt[(size_t)(tA + 32 + j) * ST];
#pragma unroll
    for (int j = 0; j < 32; ++j) {
      unsigned int zz = za[j];
      float z0 = fmaf(bf2f((unsigned short)(zz & 0xffffu)), sc0, sh0);
      float z1 = fmaf(bf2f((unsigned short)(zz >> 16)), sc1, sh1);
      hv0 = fmaxf(fmaf(u0, hv0, z0), 0.f);
      hv1 = fmaxf(fmaf(u1, hv1, z1), 0.f);
      Ht[(size_t)(tA + j) * ST] = ((unsigned int)f2bf(hv1) << 16) | f2bf(hv0);
    }
    if (blk < 3) {
#pragma unroll
      for (int j = 0; j < 32; ++j) za[j] = Zt[(size_t)(tA + 64 + j) * ST];
    }
#pragma unroll
    for (int j = 0; j < 32; ++j) {
      unsigned int zz = zb[j];
      float z0 = fmaf(bf2f((unsigned short)(zz & 0xffffu)), sc0, sh0);
      float z1 = fmaf(bf2f((unsigned short)(zz >> 16)), sc1, sh1);
      hv0 = fmaxf(fmaf(u0, hv0, z0), 0.f);
      hv1 = fmaxf(fmaf(u1, hv1, z1), 0.f);
      Ht[(size_t)(tA + 32 + j) * ST] = ((unsigned int)f2bf(hv1) << 16) | f2bf(hv0);
    }
  }
}

// ---------------- classifier ----------------
__global__ __launch_bounds__(256) void classifier_kernel(
    const unsigned short* __restrict__ hlast, const float* __restrict__ Wc,
    const float* __restrict__ bc, float* __restrict__ out) {
  __shared__ float hs[H_DIM];
  int b = blockIdx.y;
  int n = blockIdx.x * 256 + threadIdx.x;
  for (int k = threadIdx.x; k < H_DIM; k += 256)
    hs[k] = bf2f(hlast[(size_t)b * H_DIM + k]);
  __syncthreads();
  if (n < NC_DIM) {
    float acc = bc[n];
#pragma unroll 8
    for (int k = 0; k < H_DIM; ++k)
      acc = fmaf(hs[k], Wc[(size_t)k * NC_DIM + n], acc);
    out[(size_t)b * NC_DIM + n] = acc;
  }
}

extern "C" void kernel_launch(void* const* d_in, const int* in_sizes, int n_in,
                              void* d_out, int out_size, void* d_ws, size_t ws_size,
                              hipStream_t stream) {
  const float* x     = (const float*)d_in[0];
  const float* W     = (const float*)d_in[1];
  // d_in[2] = b: cancels under BatchNorm (shift-invariant)
  const float* gamma = (const float*)d_in[3];
  const float* beta  = (const float*)d_in[4];
  const float* u     = (const float*)d_in[5];
  const float* Wc    = (const float*)d_in[6];
  const float* bc    = (const float*)d_in[7];
  float* out = (float*)d_out;

  const size_t CH = (size_t)C_DIM * H_DIM;
  const size_t MH = (size_t)M_DIM * H_DIM;
  char* p = (char*)d_ws;
  unsigned short* Wt = (unsigned short*)p; p += L_DIM * CH * sizeof(unsigned short);
  unsigned short* Ha = (unsigned short*)p; p += MH * sizeof(unsigned short);
  unsigned short* Hb = (unsigned short*)p; p += MH * sizeof(unsigned short);
  unsigned short* Z  = (unsigned short*)p; p += MH * sizeof(unsigned short);
  float* psum = (float*)p; p += 128 * H_DIM * sizeof(float);
  float* psqs = (float*)p; p += 128 * H_DIM * sizeof(float);
  float* ss   = (float*)p; p += 2 * H_DIM * sizeof(float);

  f32_to_bf16_kernel<<<2048, 256, 0, stream>>>(x, Ha, (int)(MH / 4));
  wtrans_kernel<<<dim3(H_DIM / 32, C_DIM / 32, L_DIM), dim3(32, 8), 0, stream>>>(W, Wt);

  unsigned short* cur = Ha;
  unsigned short* nxt = Hb;
  for (int l = 0; l < L_DIM; ++l) {
    gemm_kernel<<<(M_DIM / 256) * (H_DIM / 256), 512, 131072, stream>>>(
        cur, Wt + (size_t)l * CH, Z, psum, psqs);
    bn_finalize_kernel<<<4, 256, 0, stream>>>(psum, psqs, gamma + (size_t)l * H_DIM,
                                              beta + (size_t)l * H_DIM, ss);
    bn_recur_kernel<<<BH_DIM / 512, 256, 0, stream>>>(Z, ss, u + (size_t)l * H_DIM, nxt);
    unsigned short* tmp = cur; cur = nxt; nxt = tmp;
  }
  classifier_kernel<<<dim3(4, B_DIM), 256, 0, stream>>>(
      cur + (size_t)(T_DIM - 1) * BH_DIM, Wc, bc, out);
}

// Round 7
// 761.474 us; speedup vs baseline: 1.0148x; 1.0148x over previous
//
#include <hip/hip_runtime.h>
#include <hip/hip_bf16.h>

#define T_DIM 256
#define B_DIM 128
#define C_DIM 1024
#define H_DIM 1024
#define L_DIM 6
#define NC_DIM 1000
#define M_DIM (T_DIM * B_DIM)    // 32768
#define BH_DIM (B_DIM * H_DIM)   // 131072

typedef __attribute__((ext_vector_type(8))) short bf16x8;
typedef __attribute__((ext_vector_type(4))) float f32x4;

__device__ __forceinline__ float bf2f(unsigned short u) {
  union { unsigned int i; float f; } v; v.i = ((unsigned int)u) << 16; return v.f;
}
__device__ __forceinline__ unsigned short f2bf(float f) {
  union { float f; unsigned int i; } v; v.f = f;
  unsigned int r = v.i + 0x7fffu + ((v.i >> 16) & 1u);  // RNE
  return (unsigned short)(r >> 16);
}

__device__ __forceinline__ void gload_lds16(const void* g, void* l) {
  __builtin_amdgcn_global_load_lds(
      (const __attribute__((address_space(1))) unsigned int*)g,
      (__attribute__((address_space(3))) unsigned int*)l, 16, 0, 0);
}

// ---------------- x f32 -> bf16 convert ----------------
__global__ __launch_bounds__(256) void f32_to_bf16_kernel(
    const float* __restrict__ in, unsigned short* __restrict__ out, int n4) {
  int stride = gridDim.x * blockDim.x;
  for (int i = blockIdx.x * blockDim.x + threadIdx.x; i < n4; i += stride) {
    float4 v = ((const float4*)in)[i];
    ushort4 o;
    o.x = f2bf(v.x); o.y = f2bf(v.y); o.z = f2bf(v.z); o.w = f2bf(v.w);
    ((ushort4*)out)[i] = o;
  }
}

// ---------------- W (L,C,H) f32 -> Wt (L,H,C) bf16 ----------------
__global__ __launch_bounds__(256) void wtrans_kernel(
    const float* __restrict__ W, unsigned short* __restrict__ Wt) {
  __shared__ float tile[32][33];
  int l = blockIdx.z;
  const float* Wl = W + (size_t)l * C_DIM * H_DIM;
  unsigned short* Wtl = Wt + (size_t)l * C_DIM * H_DIM;
  int h0 = blockIdx.x * 32, c0 = blockIdx.y * 32;
  int tx = threadIdx.x, ty = threadIdx.y;  // 32 x 8
#pragma unroll
  for (int i = 0; i < 32; i += 8)
    tile[ty + i][tx] = Wl[(size_t)(c0 + ty + i) * H_DIM + h0 + tx];
  __syncthreads();
#pragma unroll
  for (int i = 0; i < 32; i += 8)
    Wtl[(size_t)(h0 + ty + i) * C_DIM + c0 + tx] = f2bf(tile[tx][ty + i]);
}

// ---------------- GEMM 256x256, BK=64, 8-phase (4 phases/K-tile) schedule ----------------
// Z(bf16) = A(bf16, MxK) * Wt(bf16, NxK)^T, fused BN partial stats (f32-exact).
// 8 waves (2M x 4N); per-wave 128x64 out = 8x4 16x16 frags; MFMA 16x16x32.
// LDS 128 KiB: 2 K-tile buffers x {Ak0,Ak1,Bk0,Bk1} 16KB halves (k-split!).
// Per phase: {ds_read subtile || stage one half of tile t+1} -> barrier ->
//   lgkmcnt(0)+sched_barrier -> setprio+16 MFMA+setprio -> barrier.
// Counted vmcnt(4) ONLY at end of phases 2 & 4 (before the barrier):
//   ph2: guarantees {Bk1(t),Ak1(t)} landed (allowed in flight: Bk0/Ak0(t+1));
//   ph4: guarantees {Bk0,Ak0}(t+1)     (allowed in flight: Bk1/Ak1(t+1)).
// Swizzle: 16B chunk ^= (row>>1)&3 on both sides (round-3 verified: 0 conflicts).
#define NT 16  // K / 64

__global__ __launch_bounds__(512, 2) void gemm_kernel(
    const unsigned short* __restrict__ A, const unsigned short* __restrict__ Bt,
    unsigned short* __restrict__ Z, float* __restrict__ psum, float* __restrict__ psqs) {
  extern __shared__ char lds[];
  int bid = blockIdx.x;              // 512 blocks, %8==0 -> bijective XCD swizzle
  int swz = (bid & 7) * 64 + (bid >> 3);
  int tm = swz >> 2, tn = swz & 3;   // 128 x 4 tiles
  int tid = threadIdx.x;
  int wv = tid >> 6, ln = tid & 63;
  int wm = wv >> 2, wn = wv & 3;     // 2 x 4 wave grid

  const char* Apanel = (const char*)A + (size_t)tm * 256 * 2048;   // 2048B = K row
  const char* Bpanel = (const char*)Bt + (size_t)tn * 256 * 2048;

  // ---- staging addresses (pre-swizzled global source, linear LDS dest) ----
  // load j covers rows j*128 + wv*16 + (ln>>2); phys chunk = ln&3 within 64B half-row
  int srow0 = wv * 16 + (ln >> 2);
  int skey = (ln >> 3) & 3;                       // row bits 1-2
  int sclog = (ln & 3) ^ skey;                    // logical chunk to fetch
  size_t soff0 = (size_t)srow0 * 2048 + sclog * 16;
  size_t soff1 = (size_t)(128 + srow0) * 2048 + sclog * 16;
  int sdst = wv * 1024;                           // wave-uniform (+ lane*16 by HW)

  // regions within a 64KB buffer: Ak0=0, Ak1=16384, Bk0=32768, Bk1=49152
  auto stage = [&](int t, int region) {
    char* base = lds + ((t & 1) * 65536) + region * 16384;
    const char* src = (region < 2) ? Apanel : Bpanel;
    int kb = t * 128 + (region & 1) * 64;         // k-byte offset of this half
    gload_lds16(src + soff0 + kb, base + sdst);
    gload_lds16(src + soff1 + kb, base + 8192 + sdst);
  };

  // ---- fragment read offsets (proven 0-conflict pattern) ----
  int frow = ln & 15;
  int fchunk = ((ln >> 4) ^ (frow >> 1)) & 3;
  int floff = frow * 64 + (fchunk << 4);

  f32x4 acc[8][4];
  f32x4 zero = {0.f, 0.f, 0.f, 0.f};
#pragma unroll
  for (int m = 0; m < 8; ++m)
#pragma unroll
    for (int n = 0; n < 4; ++n) acc[m][n] = zero;

  bf16x8 bfr[4], af[4];
  auto readB = [&](int t, int kk) {
    const char* Bb = lds + ((t & 1) * 65536) + 32768 + kk * 16384 + wn * 4096;
#pragma unroll
    for (int n = 0; n < 4; ++n) bfr[n] = *(const bf16x8*)(Bb + n * 1024 + floff);
  };
  auto readA = [&](int t, int kk, int mq) {
    const char* Ab = lds + ((t & 1) * 65536) + kk * 16384 + wm * 8192 + mq * 4096;
#pragma unroll
    for (int i = 0; i < 4; ++i) af[i] = *(const bf16x8*)(Ab + i * 1024 + floff);
  };
  auto mfma16 = [&](int mq) {
    __builtin_amdgcn_s_setprio(1);
#pragma unroll
    for (int i = 0; i < 4; ++i)
#pragma unroll
      for (int n = 0; n < 4; ++n)
        acc[mq * 4 + i][n] =
            __builtin_amdgcn_mfma_f32_16x16x32_bf16(af[i], bfr[n], acc[mq * 4 + i][n], 0, 0, 0);
    __builtin_amdgcn_s_setprio(0);
  };

  // prologue: tile 0's 4 halves; wait for Bk0,Ak0 (vmcnt 4 = Bk1,Ak1 may fly)
  stage(0, 2); stage(0, 0); stage(0, 3); stage(0, 1);
  asm volatile("s_waitcnt vmcnt(4)" ::: "memory");
  __builtin_amdgcn_s_barrier();

  for (int t = 0; t < NT; ++t) {
    bool st = (t + 1 < NT);
    // ---- phase 1: B kk0 + A kk0 mq0 ; stage Bk0(t+1) ----
    readB(t, 0); readA(t, 0, 0);
    if (st) stage(t + 1, 2);
    __builtin_amdgcn_s_barrier();
    asm volatile("s_waitcnt lgkmcnt(0)" ::: "memory");
    __builtin_amdgcn_sched_barrier(0);
    mfma16(0);
    __builtin_amdgcn_s_barrier();
    // ---- phase 2: A kk0 mq1 ; stage Ak0(t+1) ; vmcnt(4) for kk1(t) ----
    readA(t, 0, 1);
    if (st) stage(t + 1, 0);
    __builtin_amdgcn_s_barrier();
    asm volatile("s_waitcnt lgkmcnt(0)" ::: "memory");
    __builtin_amdgcn_sched_barrier(0);
    mfma16(1);
    asm volatile("s_waitcnt vmcnt(4)" ::: "memory");
    __builtin_amdgcn_s_barrier();
    // ---- phase 3: B kk1 + A kk1 mq0 ; stage Bk1(t+1) ----
    readB(t, 1); readA(t, 1, 0);
    if (st) stage(t + 1, 3);
    __builtin_amdgcn_s_barrier();
    asm volatile("s_waitcnt lgkmcnt(0)" ::: "memory");
    __builtin_amdgcn_sched_barrier(0);
    mfma16(0);
    __builtin_amdgcn_s_barrier();
    // ---- phase 4: A kk1 mq1 ; stage Ak1(t+1) ; vmcnt(4) for kk0(t+1) ----
    readA(t, 1, 1);
    if (st) stage(t + 1, 1);
    __builtin_amdgcn_s_barrier();
    asm volatile("s_waitcnt lgkmcnt(0)" ::: "memory");
    __builtin_amdgcn_sched_barrier(0);
    mfma16(1);
    asm volatile("s_waitcnt vmcnt(4)" ::: "memory");
    __builtin_amdgcn_s_barrier();
  }

  // ---- epilogue: fused BN partial stats (exact f32) + bf16 Z write ----
  // C/D layout: col = ln&15, row = (ln>>4)*4 + reg
  float s[4], q[4];
#pragma unroll
  for (int n = 0; n < 4; ++n) {
    float sv = 0.f, qv = 0.f;
#pragma unroll
    for (int m = 0; m < 8; ++m)
#pragma unroll
      for (int r = 0; r < 4; ++r) {
        float v = acc[m][n][r];
        sv += v; qv += v * v;
      }
    s[n] = sv; q[n] = qv;
  }
#pragma unroll
  for (int n = 0; n < 4; ++n) {
    s[n] += __shfl_xor(s[n], 16); s[n] += __shfl_xor(s[n], 32);
    q[n] += __shfl_xor(q[n], 16); q[n] += __shfl_xor(q[n], 32);
  }
  float* red = (float*)lds;  // Ak0/buf0 region, dead after the loop
  if (ln < 16) {
#pragma unroll
    for (int n = 0; n < 4; ++n) {
      red[wm * 256 + wn * 64 + n * 16 + ln] = s[n];
      red[512 + wm * 256 + wn * 64 + n * 16 + ln] = q[n];
    }
  }
  __syncthreads();
  if (tid < 256) {
    psum[(size_t)tm * H_DIM + tn * 256 + tid] = red[tid] + red[256 + tid];
  } else {
    int c = tid - 256;
    psqs[(size_t)tm * H_DIM + tn * 256 + c] = red[512 + c] + red[768 + c];
  }
  // bf16 Z stores
  int r0 = tm * 256 + wm * 128 + ((ln >> 4) << 2);
  int c0 = tn * 256 + wn * 64 + (ln & 15);
#pragma unroll
  for (int m = 0; m < 8; ++m)
#pragma unroll
    for (int n = 0; n < 4; ++n) {
      unsigned short* zp = Z + (size_t)(r0 + m * 16) * H_DIM + c0 + n * 16;
#pragma unroll
      for (int r = 0; r < 4; ++r) zp[(size_t)r * H_DIM] = f2bf(acc[m][n][r]);
    }
}

// ---------------- BN finalize: sum 128 partials per channel ----------------
__global__ __launch_bounds__(256) void bn_finalize_kernel(
    const float* __restrict__ psum, const float* __restrict__ psqs,
    const float* __restrict__ gamma, const float* __restrict__ beta,
    float* __restrict__ ss) {
  int c = blockIdx.x * blockDim.x + threadIdx.x;
  float s = 0.f, q = 0.f;
  for (int i = 0; i < 128; ++i) {
    s += psum[(size_t)i * H_DIM + c];
    q += psqs[(size_t)i * H_DIM + c];
  }
  const float invN = 1.0f / (float)M_DIM;
  float mean = s * invN;
  float var = q * invN - mean * mean;
  float sc = gamma[c] * rsqrtf(var + 1e-5f);
  ss[c] = sc;
  ss[H_DIM + c] = beta[c] - mean * sc;
}

// ---------------- fused BN-apply + IndRNN recurrence (2 ch/thread, bf16 Z) ----------------
// 32-deep static double-buffered prefetch (compile-time indices, rule #20).
__global__ __launch_bounds__(256) void bn_recur_kernel(
    const unsigned short* __restrict__ Z, const float* __restrict__ ss,
    const float* __restrict__ u, unsigned short* __restrict__ Hout) {
  int i2 = blockIdx.x * 256 + threadIdx.x;  // pair index, 0..BH/2-1
  int h0 = (i2 & (H_DIM / 2 - 1)) * 2;
  float sc0 = ss[h0], sc1 = ss[h0 + 1];
  float sh0 = ss[H_DIM + h0], sh1 = ss[H_DIM + h0 + 1];
  float u0 = u[h0], u1 = u[h0 + 1];
  float hv0 = 0.f, hv1 = 0.f;
  const size_t ST = BH_DIM / 2;
  const unsigned int* Zt = (const unsigned int*)Z + i2;
  unsigned int* Ht = (unsigned int*)Hout + i2;

  unsigned int za[32], zb[32];
#pragma unroll
  for (int j = 0; j < 32; ++j) za[j] = Zt[(size_t)j * ST];

#pragma unroll
  for (int blk = 0; blk < 4; ++blk) {
    int tA = blk * 64;
#pragma unroll
    for (int j = 0; j < 32; ++j) zb[j] = Zt[(size_t)(tA + 32 + j) * ST];
#pragma unroll
    for (int j = 0; j < 32; ++j) {
      unsigned int zz = za[j];
      float z0 = fmaf(bf2f((unsigned short)(zz & 0xffffu)), sc0, sh0);
      float z1 = fmaf(bf2f((unsigned short)(zz >> 16)), sc1, sh1);
      hv0 = fmaxf(fmaf(u0, hv0, z0), 0.f);
      hv1 = fmaxf(fmaf(u1, hv1, z1), 0.f);
      Ht[(size_t)(tA + j) * ST] = ((unsigned int)f2bf(hv1) << 16) | f2bf(hv0);
    }
    if (blk < 3) {
#pragma unroll
      for (int j = 0; j < 32; ++j) za[j] = Zt[(size_t)(tA + 64 + j) * ST];
    }
#pragma unroll
    for (int j = 0; j < 32; ++j) {
      unsigned int zz = zb[j];
      float z0 = fmaf(bf2f((unsigned short)(zz & 0xffffu)), sc0, sh0);
      float z1 = fmaf(bf2f((unsigned short)(zz >> 16)), sc1, sh1);
      hv0 = fmaxf(fmaf(u0, hv0, z0), 0.f);
      hv1 = fmaxf(fmaf(u1, hv1, z1), 0.f);
      Ht[(size_t)(tA + 32 + j) * ST] = ((unsigned int)f2bf(hv1) << 16) | f2bf(hv0);
    }
  }
}

// ---------------- classifier ----------------
__global__ __launch_bounds__(256) void classifier_kernel(
    const unsigned short* __restrict__ hlast, const float* __restrict__ Wc,
    const float* __restrict__ bc, float* __restrict__ out) {
  __shared__ float hs[H_DIM];
  int b = blockIdx.y;
  int n = blockIdx.x * 256 + threadIdx.x;
  for (int k = threadIdx.x; k < H_DIM; k += 256)
    hs[k] = bf2f(hlast[(size_t)b * H_DIM + k]);
  __syncthreads();
  if (n < NC_DIM) {
    float acc = bc[n];
#pragma unroll 8
    for (int k = 0; k < H_DIM; ++k)
      acc = fmaf(hs[k], Wc[(size_t)k * NC_DIM + n], acc);
    out[(size_t)b * NC_DIM + n] = acc;
  }
}

extern "C" void kernel_launch(void* const* d_in, const int* in_sizes, int n_in,
                              void* d_out, int out_size, void* d_ws, size_t ws_size,
                              hipStream_t stream) {
  const float* x     = (const float*)d_in[0];
  const float* W     = (const float*)d_in[1];
  // d_in[2] = b: cancels under BatchNorm (shift-invariant)
  const float* gamma = (const float*)d_in[3];
  const float* beta  = (const float*)d_in[4];
  const float* u     = (const float*)d_in[5];
  const float* Wc    = (const float*)d_in[6];
  const float* bc    = (const float*)d_in[7];
  float* out = (float*)d_out;

  const size_t CH = (size_t)C_DIM * H_DIM;
  const size_t MH = (size_t)M_DIM * H_DIM;
  char* p = (char*)d_ws;
  unsigned short* Wt = (unsigned short*)p; p += L_DIM * CH * sizeof(unsigned short);
  unsigned short* Ha = (unsigned short*)p; p += MH * sizeof(unsigned short);
  unsigned short* Hb = (unsigned short*)p; p += MH * sizeof(unsigned short);
  unsigned short* Z  = (unsigned short*)p; p += MH * sizeof(unsigned short);
  float* psum = (float*)p; p += 128 * H_DIM * sizeof(float);
  float* psqs = (float*)p; p += 128 * H_DIM * sizeof(float);
  float* ss   = (float*)p; p += 2 * H_DIM * sizeof(float);

  f32_to_bf16_kernel<<<2048, 256, 0, stream>>>(x, Ha, (int)(MH / 4));
  wtrans_kernel<<<dim3(H_DIM / 32, C_DIM / 32, L_DIM), dim3(32, 8), 0, stream>>>(W, Wt);

  unsigned short* cur = Ha;
  unsigned short* nxt = Hb;
  for (int l = 0; l < L_DIM; ++l) {
    gemm_kernel<<<(M_DIM / 256) * (H_DIM / 256), 512, 131072, stream>>>(
        cur, Wt + (size_t)l * CH, Z, psum, psqs);
    bn_finalize_kernel<<<4, 256, 0, stream>>>(psum, psqs, gamma + (size_t)l * H_DIM,
                                              beta + (size_t)l * H_DIM, ss);
    bn_recur_kernel<<<BH_DIM / 512, 256, 0, stream>>>(Z, ss, u + (size_t)l * H_DIM, nxt);
    unsigned short* tmp = cur; cur = nxt; nxt = tmp;
  }
  classifier_kernel<<<dim3(4, B_DIM), 256, 0, stream>>>(
      cur + (size_t)(T_DIM - 1) * BH_DIM, Wc, bc, out);
}

// Round 8
// 755.471 us; speedup vs baseline: 1.0229x; 1.0079x over previous
//
#include <hip/hip_runtime.h>
#include <hip/hip_bf16.h>

#define T_DIM 256
#define B_DIM 128
#define C_DIM 1024
#define H_DIM 1024
#define L_DIM 6
#define NC_DIM 1000
#define M_DIM (T_DIM * B_DIM)    // 32768
#define BH_DIM (B_DIM * H_DIM)   // 131072

typedef __attribute__((ext_vector_type(8))) short bf16x8;
typedef __attribute__((ext_vector_type(4))) float f32x4;

__device__ __forceinline__ float bf2f(unsigned short u) {
  union { unsigned int i; float f; } v; v.i = ((unsigned int)u) << 16; return v.f;
}
__device__ __forceinline__ unsigned short f2bf(float f) {
  union { float f; unsigned int i; } v; v.f = f;
  unsigned int r = v.i + 0x7fffu + ((v.i >> 16) & 1u);  // RNE
  return (unsigned short)(r >> 16);
}

__device__ __forceinline__ void gload_lds16(const void* g, void* l) {
  __builtin_amdgcn_global_load_lds(
      (const __attribute__((address_space(1))) unsigned int*)g,
      (__attribute__((address_space(3))) unsigned int*)l, 16, 0, 0);
}

// ---------------- x f32 -> bf16 convert ----------------
__global__ __launch_bounds__(256) void f32_to_bf16_kernel(
    const float* __restrict__ in, unsigned short* __restrict__ out, int n4) {
  int stride = gridDim.x * blockDim.x;
  for (int i = blockIdx.x * blockDim.x + threadIdx.x; i < n4; i += stride) {
    float4 v = ((const float4*)in)[i];
    ushort4 o;
    o.x = f2bf(v.x); o.y = f2bf(v.y); o.z = f2bf(v.z); o.w = f2bf(v.w);
    ((ushort4*)out)[i] = o;
  }
}

// ---------------- W (L,C,H) f32 -> Wt (L,H,C) bf16 ----------------
__global__ __launch_bounds__(256) void wtrans_kernel(
    const float* __restrict__ W, unsigned short* __restrict__ Wt) {
  __shared__ float tile[32][33];
  int l = blockIdx.z;
  const float* Wl = W + (size_t)l * C_DIM * H_DIM;
  unsigned short* Wtl = Wt + (size_t)l * C_DIM * H_DIM;
  int h0 = blockIdx.x * 32, c0 = blockIdx.y * 32;
  int tx = threadIdx.x, ty = threadIdx.y;  // 32 x 8
#pragma unroll
  for (int i = 0; i < 32; i += 8)
    tile[ty + i][tx] = Wl[(size_t)(c0 + ty + i) * H_DIM + h0 + tx];
  __syncthreads();
#pragma unroll
  for (int i = 0; i < 32; i += 8)
    Wtl[(size_t)(h0 + ty + i) * C_DIM + c0 + tx] = f2bf(tile[tx][ty + i]);
}

// ---------------- GEMM 256x256, BK=64, 2 barriers/K-tile free-run schedule ----------------
// Z(bf16) = A(bf16, MxK) * Wt(bf16, NxK)^T, fused BN partial stats (f32-exact).
// 8 waves (2M x 4N); per-wave 128x64 out = 8x4 16x16 frags; MFMA 16x16x32.
// LDS 128 KiB: 2 K-tile buffers x {Ak0,Ak1,Bk0,Bk1} 16KB halves (k-split).
// Hazard audit (why 2 barriers/tile suffice):
//  - staging writes the OTHER buffer -> never conflicts with current-tile reads;
//  - mid-tile {vmcnt(4)+barrier}: in-order vmcnt retirement => oldest 4 own loads
//    (= Bk1(t),Ak1(t)) retired in every wave => kk1(t) globally visible;
//  - tile-end {vmcnt(4)+barrier}: retires Bk0(t+1),Ak0(t+1) => kk0(t+1) visible;
//  - barrier also proves all waves finished reading the buffer being re-staged.
// Between barriers, waves free-run: one wave's ds_reads overlap another's MFMAs.
// Swizzle: 16B chunk ^= (row>>1)&3 on both sides (round-3 verified: 0 conflicts).
#define NT 16  // K / 64

__global__ __launch_bounds__(512, 2) void gemm_kernel(
    const unsigned short* __restrict__ A, const unsigned short* __restrict__ Bt,
    unsigned short* __restrict__ Z, float* __restrict__ psum, float* __restrict__ psqs) {
  extern __shared__ char lds[];
  int bid = blockIdx.x;              // 512 blocks, %8==0 -> bijective XCD swizzle
  int swz = (bid & 7) * 64 + (bid >> 3);
  int tm = swz >> 2, tn = swz & 3;   // 128 x 4 tiles
  int tid = threadIdx.x;
  int wv = tid >> 6, ln = tid & 63;
  int wm = wv >> 2, wn = wv & 3;     // 2 x 4 wave grid

  const char* Apanel = (const char*)A + (size_t)tm * 256 * 2048;   // 2048B = K row
  const char* Bpanel = (const char*)Bt + (size_t)tn * 256 * 2048;

  // ---- staging addresses (pre-swizzled global source, linear LDS dest) ----
  int srow0 = wv * 16 + (ln >> 2);
  int skey = (ln >> 3) & 3;                       // row bits 1-2
  int sclog = (ln & 3) ^ skey;                    // logical chunk to fetch
  size_t soff0 = (size_t)srow0 * 2048 + sclog * 16;
  size_t soff1 = (size_t)(128 + srow0) * 2048 + sclog * 16;
  int sdst = wv * 1024;                           // wave-uniform (+ lane*16 by HW)

  // regions within a 64KB buffer: Ak0=0, Ak1=16384, Bk0=32768, Bk1=49152
  auto stage = [&](int t, int region) {
    char* base = lds + ((t & 1) * 65536) + region * 16384;
    const char* src = (region < 2) ? Apanel : Bpanel;
    int kb = t * 128 + (region & 1) * 64;         // k-byte offset of this half
    gload_lds16(src + soff0 + kb, base + sdst);
    gload_lds16(src + soff1 + kb, base + 8192 + sdst);
  };

  // ---- fragment read offsets (proven 0-conflict pattern) ----
  int frow = ln & 15;
  int fchunk = ((ln >> 4) ^ (frow >> 1)) & 3;
  int floff = frow * 64 + (fchunk << 4);

  f32x4 acc[8][4];
  f32x4 zero = {0.f, 0.f, 0.f, 0.f};
#pragma unroll
  for (int m = 0; m < 8; ++m)
#pragma unroll
    for (int n = 0; n < 4; ++n) acc[m][n] = zero;

  bf16x8 bfr[4], af[4];
  auto readB = [&](int t, int kk) {
    const char* Bb = lds + ((t & 1) * 65536) + 32768 + kk * 16384 + wn * 4096;
#pragma unroll
    for (int n = 0; n < 4; ++n) bfr[n] = *(const bf16x8*)(Bb + n * 1024 + floff);
  };
  auto readA = [&](int t, int kk, int mq) {
    const char* Ab = lds + ((t & 1) * 65536) + kk * 16384 + wm * 8192 + mq * 4096;
#pragma unroll
    for (int i = 0; i < 4; ++i) af[i] = *(const bf16x8*)(Ab + i * 1024 + floff);
  };
  auto mfma16 = [&](int mq) {
    __builtin_amdgcn_s_setprio(1);
#pragma unroll
    for (int i = 0; i < 4; ++i)
#pragma unroll
      for (int n = 0; n < 4; ++n)
        acc[mq * 4 + i][n] =
            __builtin_amdgcn_mfma_f32_16x16x32_bf16(af[i], bfr[n], acc[mq * 4 + i][n], 0, 0, 0);
    __builtin_amdgcn_s_setprio(0);
  };

  // prologue: tile 0's 4 halves; wait for Bk0,Ak0 (vmcnt 4 = Bk1,Ak1 may fly)
  stage(0, 2); stage(0, 0); stage(0, 3); stage(0, 1);
  asm volatile("s_waitcnt vmcnt(4)" ::: "memory");
  __builtin_amdgcn_s_barrier();

  for (int t = 0; t < NT; ++t) {
    bool st = (t + 1 < NT);
    // ---- k-half 0 (free-run: no barriers inside) ----
    readB(t, 0); readA(t, 0, 0);
    if (st) stage(t + 1, 2);                       // Bk0(t+1)
    asm volatile("s_waitcnt lgkmcnt(0)" ::: "memory");
    __builtin_amdgcn_sched_barrier(0);
    mfma16(0);
    readA(t, 0, 1);
    if (st) stage(t + 1, 0);                       // Ak0(t+1)
    asm volatile("s_waitcnt lgkmcnt(0)" ::: "memory");
    __builtin_amdgcn_sched_barrier(0);
    mfma16(1);
    asm volatile("s_waitcnt vmcnt(4)" ::: "memory");  // retires Bk1(t),Ak1(t)
    __builtin_amdgcn_s_barrier();
    // ---- k-half 1 ----
    readB(t, 1); readA(t, 1, 0);
    if (st) stage(t + 1, 3);                       // Bk1(t+1)
    asm volatile("s_waitcnt lgkmcnt(0)" ::: "memory");
    __builtin_amdgcn_sched_barrier(0);
    mfma16(0);
    readA(t, 1, 1);
    if (st) stage(t + 1, 1);                       // Ak1(t+1)
    asm volatile("s_waitcnt lgkmcnt(0)" ::: "memory");
    __builtin_amdgcn_sched_barrier(0);
    mfma16(1);
    asm volatile("s_waitcnt vmcnt(4)" ::: "memory");  // retires Bk0(t+1),Ak0(t+1)
    __builtin_amdgcn_s_barrier();
  }

  // ---- epilogue: fused BN partial stats (exact f32) + bf16 Z write ----
  // C/D layout: col = ln&15, row = (ln>>4)*4 + reg
  float s[4], q[4];
#pragma unroll
  for (int n = 0; n < 4; ++n) {
    float sv = 0.f, qv = 0.f;
#pragma unroll
    for (int m = 0; m < 8; ++m)
#pragma unroll
      for (int r = 0; r < 4; ++r) {
        float v = acc[m][n][r];
        sv += v; qv += v * v;
      }
    s[n] = sv; q[n] = qv;
  }
#pragma unroll
  for (int n = 0; n < 4; ++n) {
    s[n] += __shfl_xor(s[n], 16); s[n] += __shfl_xor(s[n], 32);
    q[n] += __shfl_xor(q[n], 16); q[n] += __shfl_xor(q[n], 32);
  }
  float* red = (float*)lds;  // buffer-0 Ak0 region, dead after the loop
  if (ln < 16) {
#pragma unroll
    for (int n = 0; n < 4; ++n) {
      red[wm * 256 + wn * 64 + n * 16 + ln] = s[n];
      red[512 + wm * 256 + wn * 64 + n * 16 + ln] = q[n];
    }
  }
  __syncthreads();
  if (tid < 256) {
    psum[(size_t)tm * H_DIM + tn * 256 + tid] = red[tid] + red[256 + tid];
  } else {
    int c = tid - 256;
    psqs[(size_t)tm * H_DIM + tn * 256 + c] = red[512 + c] + red[768 + c];
  }
  // bf16 Z stores
  int r0 = tm * 256 + wm * 128 + ((ln >> 4) << 2);
  int c0 = tn * 256 + wn * 64 + (ln & 15);
#pragma unroll
  for (int m = 0; m < 8; ++m)
#pragma unroll
    for (int n = 0; n < 4; ++n) {
      unsigned short* zp = Z + (size_t)(r0 + m * 16) * H_DIM + c0 + n * 16;
#pragma unroll
      for (int r = 0; r < 4; ++r) zp[(size_t)r * H_DIM] = f2bf(acc[m][n][r]);
    }
}

// ---------------- BN finalize: sum 128 partials per channel ----------------
__global__ __launch_bounds__(256) void bn_finalize_kernel(
    const float* __restrict__ psum, const float* __restrict__ psqs,
    const float* __restrict__ gamma, const float* __restrict__ beta,
    float* __restrict__ ss) {
  int c = blockIdx.x * blockDim.x + threadIdx.x;
  float s = 0.f, q = 0.f;
  for (int i = 0; i < 128; ++i) {
    s += psum[(size_t)i * H_DIM + c];
    q += psqs[(size_t)i * H_DIM + c];
  }
  const float invN = 1.0f / (float)M_DIM;
  float mean = s * invN;
  float var = q * invN - mean * mean;
  float sc = gamma[c] * rsqrtf(var + 1e-5f);
  ss[c] = sc;
  ss[H_DIM + c] = beta[c] - mean * sc;
}

// ---------------- fused BN-apply + IndRNN recurrence (1 ch/thread, bf16 Z) ----------------
// 512 blocks (8 waves/CU, 2x round-7's occupancy); 32-deep static double-buffered
// prefetch (compile-time indices, rule #20). Loads/stores: 64 lanes x 2B = 128B/inst.
__global__ __launch_bounds__(256) void bn_recur_kernel(
    const unsigned short* __restrict__ Z, const float* __restrict__ ss,
    const float* __restrict__ u, unsigned short* __restrict__ Hout) {
  int i = blockIdx.x * 256 + threadIdx.x;   // 0..BH-1
  int h = i & (H_DIM - 1);
  float sc = ss[h], sh = ss[H_DIM + h], uu = u[h];
  float hv = 0.f;
  const unsigned short* Zt = Z + i;
  unsigned short* Ht = Hout + i;

  unsigned short za[32], zb[32];
#pragma unroll
  for (int j = 0; j < 32; ++j) za[j] = Zt[(size_t)j * BH_DIM];

#pragma unroll
  for (int blk = 0; blk < 4; ++blk) {
    int tA = blk * 64;
#pragma unroll
    for (int j = 0; j < 32; ++j) zb[j] = Zt[(size_t)(tA + 32 + j) * BH_DIM];
#pragma unroll
    for (int j = 0; j < 32; ++j) {
      float z = fmaf(bf2f(za[j]), sc, sh);
      hv = fmaxf(fmaf(uu, hv, z), 0.f);
      Ht[(size_t)(tA + j) * BH_DIM] = f2bf(hv);
    }
    if (blk < 3) {
#pragma unroll
      for (int j = 0; j < 32; ++j) za[j] = Zt[(size_t)(tA + 64 + j) * BH_DIM];
    }
#pragma unroll
    for (int j = 0; j < 32; ++j) {
      float z = fmaf(bf2f(zb[j]), sc, sh);
      hv = fmaxf(fmaf(uu, hv, z), 0.f);
      Ht[(size_t)(tA + 32 + j) * BH_DIM] = f2bf(hv);
    }
  }
}

// ---------------- classifier ----------------
__global__ __launch_bounds__(256) void classifier_kernel(
    const unsigned short* __restrict__ hlast, const float* __restrict__ Wc,
    const float* __restrict__ bc, float* __restrict__ out) {
  __shared__ float hs[H_DIM];
  int b = blockIdx.y;
  int n = blockIdx.x * 256 + threadIdx.x;
  for (int k = threadIdx.x; k < H_DIM; k += 256)
    hs[k] = bf2f(hlast[(size_t)b * H_DIM + k]);
  __syncthreads();
  if (n < NC_DIM) {
    float acc = bc[n];
#pragma unroll 8
    for (int k = 0; k < H_DIM; ++k)
      acc = fmaf(hs[k], Wc[(size_t)k * NC_DIM + n], acc);
    out[(size_t)b * NC_DIM + n] = acc;
  }
}

extern "C" void kernel_launch(void* const* d_in, const int* in_sizes, int n_in,
                              void* d_out, int out_size, void* d_ws, size_t ws_size,
                              hipStream_t stream) {
  const float* x     = (const float*)d_in[0];
  const float* W     = (const float*)d_in[1];
  // d_in[2] = b: cancels under BatchNorm (shift-invariant)
  const float* gamma = (const float*)d_in[3];
  const float* beta  = (const float*)d_in[4];
  const float* u     = (const float*)d_in[5];
  const float* Wc    = (const float*)d_in[6];
  const float* bc    = (const float*)d_in[7];
  float* out = (float*)d_out;

  const size_t CH = (size_t)C_DIM * H_DIM;
  const size_t MH = (size_t)M_DIM * H_DIM;
  char* p = (char*)d_ws;
  unsigned short* Wt = (unsigned short*)p; p += L_DIM * CH * sizeof(unsigned short);
  unsigned short* Ha = (unsigned short*)p; p += MH * sizeof(unsigned short);
  unsigned short* Hb = (unsigned short*)p; p += MH * sizeof(unsigned short);
  unsigned short* Z  = (unsigned short*)p; p += MH * sizeof(unsigned short);
  float* psum = (float*)p; p += 128 * H_DIM * sizeof(float);
  float* psqs = (float*)p; p += 128 * H_DIM * sizeof(float);
  float* ss   = (float*)p; p += 2 * H_DIM * sizeof(float);

  f32_to_bf16_kernel<<<2048, 256, 0, stream>>>(x, Ha, (int)(MH / 4));
  wtrans_kernel<<<dim3(H_DIM / 32, C_DIM / 32, L_DIM), dim3(32, 8), 0, stream>>>(W, Wt);

  unsigned short* cur = Ha;
  unsigned short* nxt = Hb;
  for (int l = 0; l < L_DIM; ++l) {
    gemm_kernel<<<(M_DIM / 256) * (H_DIM / 256), 512, 131072, stream>>>(
        cur, Wt + (size_t)l * CH, Z, psum, psqs);
    bn_finalize_kernel<<<4, 256, 0, stream>>>(psum, psqs, gamma + (size_t)l * H_DIM,
                                              beta + (size_t)l * H_DIM, ss);
    bn_recur_kernel<<<BH_DIM / 256, 256, 0, stream>>>(Z, ss, u + (size_t)l * H_DIM, nxt);
    unsigned short* tmp = cur; cur = nxt; nxt = tmp;
  }
  classifier_kernel<<<dim3(4, B_DIM), 256, 0, stream>>>(
      cur + (size_t)(T_DIM - 1) * BH_DIM, Wc, bc, out);
}

// Round 9
// 752.973 us; speedup vs baseline: 1.0263x; 1.0033x over previous
//
#include <hip/hip_runtime.h>
#include <hip/hip_bf16.h>

#define T_DIM 256
#define B_DIM 128
#define C_DIM 1024
#define H_DIM 1024
#define L_DIM 6
#define NC_DIM 1000
#define M_DIM (T_DIM * B_DIM)    // 32768
#define BH_DIM (B_DIM * H_DIM)   // 131072

typedef __attribute__((ext_vector_type(8))) short bf16x8;
typedef __attribute__((ext_vector_type(4))) float f32x4;

__device__ __forceinline__ float bf2f(unsigned short u) {
  union { unsigned int i; float f; } v; v.i = ((unsigned int)u) << 16; return v.f;
}
__device__ __forceinline__ unsigned short f2bf(float f) {
  union { float f; unsigned int i; } v; v.f = f;
  unsigned int r = v.i + 0x7fffu + ((v.i >> 16) & 1u);  // RNE
  return (unsigned short)(r >> 16);
}

__device__ __forceinline__ void gload_lds16(const void* g, void* l) {
  __builtin_amdgcn_global_load_lds(
      (const __attribute__((address_space(1))) unsigned int*)g,
      (__attribute__((address_space(3))) unsigned int*)l, 16, 0, 0);
}

// ---------------- x f32 -> bf16 convert ----------------
__global__ __launch_bounds__(256) void f32_to_bf16_kernel(
    const float* __restrict__ in, unsigned short* __restrict__ out, int n4) {
  int stride = gridDim.x * blockDim.x;
  for (int i = blockIdx.x * blockDim.x + threadIdx.x; i < n4; i += stride) {
    float4 v = ((const float4*)in)[i];
    ushort4 o;
    o.x = f2bf(v.x); o.y = f2bf(v.y); o.z = f2bf(v.z); o.w = f2bf(v.w);
    ((ushort4*)out)[i] = o;
  }
}

// ---------------- W (L,C,H) f32 -> Wt (L,H,C) bf16 ----------------
__global__ __launch_bounds__(256) void wtrans_kernel(
    const float* __restrict__ W, unsigned short* __restrict__ Wt) {
  __shared__ float tile[32][33];
  int l = blockIdx.z;
  const float* Wl = W + (size_t)l * C_DIM * H_DIM;
  unsigned short* Wtl = Wt + (size_t)l * C_DIM * H_DIM;
  int h0 = blockIdx.x * 32, c0 = blockIdx.y * 32;
  int tx = threadIdx.x, ty = threadIdx.y;  // 32 x 8
#pragma unroll
  for (int i = 0; i < 32; i += 8)
    tile[ty + i][tx] = Wl[(size_t)(c0 + ty + i) * H_DIM + h0 + tx];
  __syncthreads();
#pragma unroll
  for (int i = 0; i < 32; i += 8)
    Wtl[(size_t)(h0 + ty + i) * C_DIM + c0 + tx] = f2bf(tile[tx][ty + i]);
}

// ---------------- GEMM 256x256, BK=32, 4-buffer, compiler-scheduled pipeline ----------------
// Z(bf16) = A(bf16, MxK) * Wt(bf16, NxK)^T, fused BN partial stats (f32-exact).
// 8 waves (2M x 4N); per-wave 128x64 out = 8x4 16x16 frags; MFMA 16x16x32.
// LDS 128 KiB = 4 K-tile buffers x 32KB {A 16KB, B 16KB}.
// NO manual lgkmcnt: ds_reads issued ONE BATCH AHEAD into named reg sets
// (aP/aQ/bX); the compiler's fine-grained counted lgkmcnt lets batch N+1's
// reads overlap batch N's MFMA cluster (within-wave ILP).
// ONE barrier + counted vmcnt per tile. Visibility invariant: entering tile t,
// tile t+1 fully staged (stage t+3 during t; vmcnt(4) at tile end retires t+2)
// => read-ahead of tile t+1 before the end barrier is safe. Buffer (t+3)&3
// overwrite is WAR-safe: its last readers finished before end-of-(t-1) barrier.
// Swizzle: 16B chunk ^= (row>>1)&3 both sides (round-3 verified: 0 conflicts).
#define NT 32  // K / 32

__global__ __launch_bounds__(512, 2) void gemm_kernel(
    const unsigned short* __restrict__ A, const unsigned short* __restrict__ Bt,
    unsigned short* __restrict__ Z, float* __restrict__ psum, float* __restrict__ psqs) {
  extern __shared__ char lds[];
  int bid = blockIdx.x;              // 512 blocks, %8==0 -> bijective XCD swizzle
  int swz = (bid & 7) * 64 + (bid >> 3);
  int tm = swz >> 2, tn = swz & 3;   // 128 x 4 tiles
  int tid = threadIdx.x;
  int wv = tid >> 6, ln = tid & 63;
  int wm = wv >> 2, wn = wv & 3;     // 2 x 4 wave grid

  const char* Apanel = (const char*)A + (size_t)tm * 256 * 2048;   // 2048B = K row
  const char* Bpanel = (const char*)Bt + (size_t)tn * 256 * 2048;

  // ---- staging addresses (pre-swizzled global source, linear LDS dest) ----
  int p0 = wv * 1024 + ln * 16;           // byte within an 8KB (128-row) half
  int l0 = p0 ^ (((p0 >> 7) & 3) << 4);   // involution: chunk ^= (row>>1)&3
  size_t ro0 = (size_t)(p0 >> 6) * 2048 + (l0 & 63);          // rows 0..127
  size_t ro1 = (size_t)(128 + (p0 >> 6)) * 2048 + (l0 & 63);  // rows 128..255
  int sdst = wv * 1024;                   // wave-uniform (+ lane*16 by HW)

  auto stage = [&](int t) {               // one 32KB K-tile: A 16KB + B 16KB
    char* base = lds + ((t & 3) * 32768);
    int kb = t * 64;                      // 32 k-elems = 64 bytes
    gload_lds16(Apanel + ro0 + kb, base + sdst);
    gload_lds16(Apanel + ro1 + kb, base + 8192 + sdst);
    gload_lds16(Bpanel + ro0 + kb, base + 16384 + sdst);
    gload_lds16(Bpanel + ro1 + kb, base + 16384 + 8192 + sdst);
  };

  // ---- fragment read offsets (proven 0-conflict pattern) ----
  int frow = ln & 15;
  int fchunk = ((ln >> 4) ^ (frow >> 1)) & 3;
  int floff = frow * 64 + (fchunk << 4);

  f32x4 acc[8][4];
  f32x4 zero = {0.f, 0.f, 0.f, 0.f};
#pragma unroll
  for (int m = 0; m < 8; ++m)
#pragma unroll
    for (int n = 0; n < 4; ++n) acc[m][n] = zero;

  bf16x8 bX[4], aP[4], aQ[4];
  auto readB_to = [&](int t, bf16x8* d) {
    const char* Bb = lds + ((t & 3) * 32768) + 16384 + wn * 4096;
#pragma unroll
    for (int n = 0; n < 4; ++n) d[n] = *(const bf16x8*)(Bb + n * 1024 + floff);
  };
  auto readA_to = [&](int t, int mq, bf16x8* d) {
    const char* Ab = lds + ((t & 3) * 32768) + wm * 8192 + mq * 4096;
#pragma unroll
    for (int i = 0; i < 4; ++i) d[i] = *(const bf16x8*)(Ab + i * 1024 + floff);
  };

  // prologue: tiles 0,1,2 staged (12 loads); retire 0,1 (vmcnt 4 = tile 2 flies)
  stage(0); stage(1); stage(2);
  asm volatile("s_waitcnt vmcnt(4)" ::: "memory");
  __builtin_amdgcn_s_barrier();
  readB_to(0, bX); readA_to(0, 0, aP);

  for (int t = 0; t < NT; ++t) {
    readA_to(t, 1, aQ);                    // batch1: overlaps cluster0 below
    if (t <= NT - 4) stage(t + 3);
    __builtin_amdgcn_s_setprio(1);
#pragma unroll
    for (int i = 0; i < 4; ++i)
#pragma unroll
      for (int n = 0; n < 4; ++n)
        acc[i][n] = __builtin_amdgcn_mfma_f32_16x16x32_bf16(aP[i], bX[n], acc[i][n], 0, 0, 0);
    __builtin_amdgcn_s_setprio(0);
    __builtin_amdgcn_s_setprio(1);
#pragma unroll
    for (int i = 0; i < 4; ++i)
#pragma unroll
      for (int n = 0; n < 4; ++n)
        acc[4 + i][n] = __builtin_amdgcn_mfma_f32_16x16x32_bf16(aQ[i], bX[n], acc[4 + i][n], 0, 0, 0);
    __builtin_amdgcn_s_setprio(0);
    if (t < NT - 1) {
      readB_to(t + 1, bX); readA_to(t + 1, 0, aP);   // batch0(t+1): t+1 visible
      if (t <= NT - 4) { asm volatile("s_waitcnt vmcnt(4)" ::: "memory"); }
      else             { asm volatile("s_waitcnt vmcnt(0)" ::: "memory"); }
      __builtin_amdgcn_s_barrier();        // retires staging(t+2) -> visible
    }
  }

  // ---- epilogue: fused BN partial stats (exact f32) + bf16 Z write ----
  // C/D layout: col = ln&15, row = (ln>>4)*4 + reg
  float s[4], q[4];
#pragma unroll
  for (int n = 0; n < 4; ++n) {
    float sv = 0.f, qv = 0.f;
#pragma unroll
    for (int m = 0; m < 8; ++m)
#pragma unroll
      for (int r = 0; r < 4; ++r) {
        float v = acc[m][n][r];
        sv += v; qv += v * v;
      }
    s[n] = sv; q[n] = qv;
  }
#pragma unroll
  for (int n = 0; n < 4; ++n) {
    s[n] += __shfl_xor(s[n], 16); s[n] += __shfl_xor(s[n], 32);
    q[n] += __shfl_xor(q[n], 16); q[n] += __shfl_xor(q[n], 32);
  }
  float* red = (float*)lds;  // buffer 0 (last read at tile 28): dead here
  if (ln < 16) {
#pragma unroll
    for (int n = 0; n < 4; ++n) {
      red[wm * 256 + wn * 64 + n * 16 + ln] = s[n];
      red[512 + wm * 256 + wn * 64 + n * 16 + ln] = q[n];
    }
  }
  __syncthreads();
  if (tid < 256) {
    psum[(size_t)tm * H_DIM + tn * 256 + tid] = red[tid] + red[256 + tid];
  } else {
    int c = tid - 256;
    psqs[(size_t)tm * H_DIM + tn * 256 + c] = red[512 + c] + red[768 + c];
  }
  // bf16 Z stores
  int r0 = tm * 256 + wm * 128 + ((ln >> 4) << 2);
  int c0 = tn * 256 + wn * 64 + (ln & 15);
#pragma unroll
  for (int m = 0; m < 8; ++m)
#pragma unroll
    for (int n = 0; n < 4; ++n) {
      unsigned short* zp = Z + (size_t)(r0 + m * 16) * H_DIM + c0 + n * 16;
#pragma unroll
      for (int r = 0; r < 4; ++r) zp[(size_t)r * H_DIM] = f2bf(acc[m][n][r]);
    }
}

// ---------------- BN finalize: sum 128 partials per channel ----------------
__global__ __launch_bounds__(256) void bn_finalize_kernel(
    const float* __restrict__ psum, const float* __restrict__ psqs,
    const float* __restrict__ gamma, const float* __restrict__ beta,
    float* __restrict__ ss) {
  int c = blockIdx.x * blockDim.x + threadIdx.x;
  float s = 0.f, q = 0.f;
  for (int i = 0; i < 128; ++i) {
    s += psum[(size_t)i * H_DIM + c];
    q += psqs[(size_t)i * H_DIM + c];
  }
  const float invN = 1.0f / (float)M_DIM;
  float mean = s * invN;
  float var = q * invN - mean * mean;
  float sc = gamma[c] * rsqrtf(var + 1e-5f);
  ss[c] = sc;
  ss[H_DIM + c] = beta[c] - mean * sc;
}

// ---------------- fused BN-apply + IndRNN recurrence (1 ch/thread, bf16 Z) ----------------
// 512 blocks (8 waves/CU); 32-deep static double-buffered prefetch (rule #20).
__global__ __launch_bounds__(256) void bn_recur_kernel(
    const unsigned short* __restrict__ Z, const float* __restrict__ ss,
    const float* __restrict__ u, unsigned short* __restrict__ Hout) {
  int i = blockIdx.x * 256 + threadIdx.x;   // 0..BH-1
  int h = i & (H_DIM - 1);
  float sc = ss[h], sh = ss[H_DIM + h], uu = u[h];
  float hv = 0.f;
  const unsigned short* Zt = Z + i;
  unsigned short* Ht = Hout + i;

  unsigned short za[32], zb[32];
#pragma unroll
  for (int j = 0; j < 32; ++j) za[j] = Zt[(size_t)j * BH_DIM];

#pragma unroll
  for (int blk = 0; blk < 4; ++blk) {
    int tA = blk * 64;
#pragma unroll
    for (int j = 0; j < 32; ++j) zb[j] = Zt[(size_t)(tA + 32 + j) * BH_DIM];
#pragma unroll
    for (int j = 0; j < 32; ++j) {
      float z = fmaf(bf2f(za[j]), sc, sh);
      hv = fmaxf(fmaf(uu, hv, z), 0.f);
      Ht[(size_t)(tA + j) * BH_DIM] = f2bf(hv);
    }
    if (blk < 3) {
#pragma unroll
      for (int j = 0; j < 32; ++j) za[j] = Zt[(size_t)(tA + 64 + j) * BH_DIM];
    }
#pragma unroll
    for (int j = 0; j < 32; ++j) {
      float z = fmaf(bf2f(zb[j]), sc, sh);
      hv = fmaxf(fmaf(uu, hv, z), 0.f);
      Ht[(size_t)(tA + 32 + j) * BH_DIM] = f2bf(hv);
    }
  }
}

// ---------------- classifier ----------------
__global__ __launch_bounds__(256) void classifier_kernel(
    const unsigned short* __restrict__ hlast, const float* __restrict__ Wc,
    const float* __restrict__ bc, float* __restrict__ out) {
  __shared__ float hs[H_DIM];
  int b = blockIdx.y;
  int n = blockIdx.x * 256 + threadIdx.x;
  for (int k = threadIdx.x; k < H_DIM; k += 256)
    hs[k] = bf2f(hlast[(size_t)b * H_DIM + k]);
  __syncthreads();
  if (n < NC_DIM) {
    float acc = bc[n];
#pragma unroll 8
    for (int k = 0; k < H_DIM; ++k)
      acc = fmaf(hs[k], Wc[(size_t)k * NC_DIM + n], acc);
    out[(size_t)b * NC_DIM + n] = acc;
  }
}

extern "C" void kernel_launch(void* const* d_in, const int* in_sizes, int n_in,
                              void* d_out, int out_size, void* d_ws, size_t ws_size,
                              hipStream_t stream) {
  const float* x     = (const float*)d_in[0];
  const float* W     = (const float*)d_in[1];
  // d_in[2] = b: cancels under BatchNorm (shift-invariant)
  const float* gamma = (const float*)d_in[3];
  const float* beta  = (const float*)d_in[4];
  const float* u     = (const float*)d_in[5];
  const float* Wc    = (const float*)d_in[6];
  const float* bc    = (const float*)d_in[7];
  float* out = (float*)d_out;

  const size_t CH = (size_t)C_DIM * H_DIM;
  const size_t MH = (size_t)M_DIM * H_DIM;
  char* p = (char*)d_ws;
  unsigned short* Wt = (unsigned short*)p; p += L_DIM * CH * sizeof(unsigned short);
  unsigned short* Ha = (unsigned short*)p; p += MH * sizeof(unsigned short);
  unsigned short* Hb = (unsigned short*)p; p += MH * sizeof(unsigned short);
  unsigned short* Z  = (unsigned short*)p; p += MH * sizeof(unsigned short);
  float* psum = (float*)p; p += 128 * H_DIM * sizeof(float);
  float* psqs = (float*)p; p += 128 * H_DIM * sizeof(float);
  float* ss   = (float*)p; p += 2 * H_DIM * sizeof(float);

  f32_to_bf16_kernel<<<2048, 256, 0, stream>>>(x, Ha, (int)(MH / 4));
  wtrans_kernel<<<dim3(H_DIM / 32, C_DIM / 32, L_DIM), dim3(32, 8), 0, stream>>>(W, Wt);

  unsigned short* cur = Ha;
  unsigned short* nxt = Hb;
  for (int l = 0; l < L_DIM; ++l) {
    gemm_kernel<<<(M_DIM / 256) * (H_DIM / 256), 512, 131072, stream>>>(
        cur, Wt + (size_t)l * CH, Z, psum, psqs);
    bn_finalize_kernel<<<4, 256, 0, stream>>>(psum, psqs, gamma + (size_t)l * H_DIM,
                                              beta + (size_t)l * H_DIM, ss);
    bn_recur_kernel<<<BH_DIM / 256, 256, 0, stream>>>(Z, ss, u + (size_t)l * H_DIM, nxt);
    unsigned short* tmp = cur; cur = nxt; nxt = tmp;
  }
  classifier_kernel<<<dim3(4, B_DIM), 256, 0, stream>>>(
      cur + (size_t)(T_DIM - 1) * BH_DIM, Wc, bc, out);
}